// Round 1
// baseline (956.154 us; speedup 1.0000x reference)
//
#include <hip/hip_runtime.h>
#include <hip/hip_bf16.h>

#define S 2048
#define B 2
#define D 2048
#define H 16
#define HD 128
#define N3 6144   // 3*D
#define KD 2048   // GEMM K dim

typedef __hip_bfloat16 bf16;
typedef float f32x4 __attribute__((ext_vector_type(4)));
typedef short short8 __attribute__((ext_vector_type(8)));

__device__ __forceinline__ void gload16(const void* g, void* l) {
    __builtin_amdgcn_global_load_lds((const __attribute__((address_space(1))) void*)g,
                                     (__attribute__((address_space(3))) void*)l, 16, 0, 0);
}

// ---------------- convert kernels ----------------
__global__ __launch_bounds__(256) void cvt_x_kernel(const float* __restrict__ x, bf16* __restrict__ xb) {
    int i = blockIdx.x * 256 + threadIdx.x;   // over [S][B][D]
    int d  = i & (D - 1);
    int sb = i >> 11;        // s*B + b
    int b  = sb & (B - 1);
    int s  = sb >> 1;
    xb[((size_t)(b * S + s) << 11) + d] = __float2bfloat16(x[i]);
}

__global__ __launch_bounds__(256) void cvt_w_kernel(const float* __restrict__ in, bf16* __restrict__ o, int n) {
    for (int i = blockIdx.x * blockDim.x + threadIdx.x; i < n; i += gridDim.x * blockDim.x)
        o[i] = __float2bfloat16(in[i]);
}

// ---------------- GEMM: out[m][n] = sum_k A[m][k] * W[n][k] + bias[n] ----------------
// MODE 0: QKV epilogue (scatter to q,k [B,H,S,HD] bf16 and vT [B,H,HD,S] bf16)
// MODE 1: fp32 epilogue to d_out in [S,B,D] layout
template <int MODE>
__global__ __launch_bounds__(256, 2) void gemm_bt(
    const bf16* __restrict__ A, const bf16* __restrict__ W, const float* __restrict__ bias,
    bf16* __restrict__ oq, bf16* __restrict__ ok, bf16* __restrict__ ovT,
    float* __restrict__ oOut)
{
    __shared__ __align__(16) bf16 At[128 * 32];
    __shared__ __align__(16) bf16 Bt[128 * 32];
    const int tid = threadIdx.x;
    const int w = tid >> 6, l = tid & 63;
    const int wm = w >> 1, wn = w & 1;
    const int l15 = l & 15, l4 = l >> 4;
    const int tileN = blockIdx.x * 128;
    const int tileM = blockIdx.y * 128;

    const int lr = l >> 2;          // row-within-16-row-chunk
    const int lc = (l & 3) * 8;     // k elem offset

    f32x4 acc[4][4] = {};

    for (int kt = 0; kt < KD / 32; ++kt) {
        const int k0 = kt * 32;
#pragma unroll
        for (int c = 0; c < 2; ++c) {
            const int chunk = c * 4 + w;               // 0..7, wave-uniform
            const int grow = chunk * 16 + lr;          // 0..127
            gload16(A + (size_t)(tileM + grow) * KD + k0 + lc, (char*)At + chunk * 1024);
            gload16(W + (size_t)(tileN + grow) * KD + k0 + lc, (char*)Bt + chunk * 1024);
        }
        __syncthreads();
        short8 af[4], bfr[4];
#pragma unroll
        for (int i = 0; i < 4; ++i)
            af[i] = *(const short8*)&At[(wm * 64 + i * 16 + l15) * 32 + l4 * 8];
#pragma unroll
        for (int j = 0; j < 4; ++j)
            bfr[j] = *(const short8*)&Bt[(wn * 64 + j * 16 + l15) * 32 + l4 * 8];
#pragma unroll
        for (int i = 0; i < 4; ++i)
#pragma unroll
            for (int j = 0; j < 4; ++j)
                acc[i][j] = __builtin_amdgcn_mfma_f32_16x16x32_bf16(af[i], bfr[j], acc[i][j], 0, 0, 0);
        __syncthreads();
    }

    // epilogue
#pragma unroll
    for (int i = 0; i < 4; ++i) {
#pragma unroll
        for (int j = 0; j < 4; ++j) {
            const int ncol = tileN + wn * 64 + j * 16 + l15;
            const float bv = bias[ncol];
#pragma unroll
            for (int r = 0; r < 4; ++r) {
                const int m = tileM + wm * 64 + i * 16 + l4 * 4 + r;
                const float val = acc[i][j][r] + bv;
                if (MODE == 0) {
                    const int b_ = m >> 11, s_ = m & (S - 1);
                    const int which = ncol >> 11;
                    const int hh = (ncol >> 7) & (H - 1);
                    const int hd = ncol & (HD - 1);
                    const int bh = b_ * H + hh;
                    if (which == 0)      oq[((size_t)bh * S + s_) * HD + hd] = __float2bfloat16(val);
                    else if (which == 1) ok[((size_t)bh * S + s_) * HD + hd] = __float2bfloat16(val);
                    else                 ovT[((size_t)bh * HD + hd) * S + s_] = __float2bfloat16(val);
                } else {
                    const int b_ = m >> 11, s_ = m & (S - 1);
                    oOut[((size_t)s_ * B + b_) * D + ncol] = val;
                }
            }
        }
    }
}

// ---------------- fused LayerNorm (over HD) + RoPE for q and k, in place ----------------
__global__ __launch_bounds__(256) void ln_rope_kernel(
    bf16* __restrict__ q, bf16* __restrict__ k,
    const float* __restrict__ fc,
    const float* __restrict__ qw, const float* __restrict__ qb,
    const float* __restrict__ kw, const float* __restrict__ kb)
{
    const int tid = threadIdx.x;
    const int w = tid >> 6, l = tid & 63;
    const int row = blockIdx.x * 4 + w;      // bh*S + s, 0..65535
    const int s_ = row & (S - 1);
    const size_t base = (size_t)row * HD;
    const float f0 = fc[s_ * HD + 2 * l];
    const float f1 = fc[s_ * HD + 2 * l + 1];

#pragma unroll
    for (int which = 0; which < 2; ++which) {
        bf16* p = which == 0 ? q : k;
        const float* gw = which == 0 ? qw : kw;
        const float* gb = which == 0 ? qb : kb;
        float x0 = __bfloat162float(p[base + 2 * l]);
        float x1 = __bfloat162float(p[base + 2 * l + 1]);
        float sm = x0 + x1;
#pragma unroll
        for (int msk = 1; msk < 64; msk <<= 1) sm += __shfl_xor(sm, msk);
        const float mu = sm * (1.0f / HD);
        const float d0 = x0 - mu, d1 = x1 - mu;
        float vs = d0 * d0 + d1 * d1;
#pragma unroll
        for (int msk = 1; msk < 64; msk <<= 1) vs += __shfl_xor(vs, msk);
        const float rstd = rsqrtf(vs * (1.0f / HD) + 1e-5f);
        const float n0 = d0 * rstd * gw[2 * l] + gb[2 * l];
        const float n1 = d1 * rstd * gw[2 * l + 1] + gb[2 * l + 1];
        p[base + 2 * l]     = __float2bfloat16(n0 * f0 - n1 * f1);
        p[base + 2 * l + 1] = __float2bfloat16(n1 * f0 + n0 * f1);
    }
}

// ---------------- causal flash attention ----------------
// grid: (S/64, B*H), block 256 (4 waves, 16 q-rows each)
__global__ __launch_bounds__(256, 2) void attn_kernel(
    const bf16* __restrict__ q, const bf16* __restrict__ k, const bf16* __restrict__ vT,
    bf16* __restrict__ out)
{
    __shared__ __align__(16) bf16 P[4][16][72];
    const int tid = threadIdx.x, w = tid >> 6, l = tid & 63;
    const int l15 = l & 15, l4 = l >> 4;
    const int bh = blockIdx.y;
    const int b_ = bh >> 4, hh = bh & (H - 1);
    const int qbase = blockIdx.x * 64;
    const int qr0 = qbase + w * 16;
    const size_t hQ = (size_t)bh * S * HD;
    const size_t hV = (size_t)bh * HD * S;

    short8 aq[4];
#pragma unroll
    for (int c = 0; c < 4; ++c)
        aq[c] = *(const short8*)&q[hQ + (size_t)(qr0 + l15) * HD + c * 32 + l4 * 8];

    f32x4 o[8] = {};
    float mrun[4], lrun[4];
#pragma unroll
    for (int r = 0; r < 4; ++r) { mrun[r] = -1e30f; lrun[r] = 0.0f; }

    const int nkv = qbase / 64 + 1;
    for (int kvt = 0; kvt < nkv; ++kvt) {
        const int kvb = kvt * 64;
        f32x4 sacc[4] = {};
#pragma unroll
        for (int c = 0; c < 4; ++c) {
#pragma unroll
            for (int n = 0; n < 4; ++n) {
                short8 bk = *(const short8*)&k[hQ + (size_t)(kvb + n * 16 + l15) * HD + c * 32 + l4 * 8];
                sacc[n] = __builtin_amdgcn_mfma_f32_16x16x32_bf16(aq[c], bk, sacc[n], 0, 0, 0);
            }
        }
        const float sc = 0.08838834764831845f; // 1/sqrt(128)
        const bool diag = (kvb == qbase);
#pragma unroll
        for (int n = 0; n < 4; ++n)
#pragma unroll
            for (int r = 0; r < 4; ++r) {
                float sv = sacc[n][r] * sc;
                if (diag && (kvb + n * 16 + l15 > qr0 + l4 * 4 + r)) sv = -1e30f;
                sacc[n][r] = sv;
            }
        float pscale[4];
#pragma unroll
        for (int r = 0; r < 4; ++r) {
            float mx = fmaxf(fmaxf(sacc[0][r], sacc[1][r]), fmaxf(sacc[2][r], sacc[3][r]));
#pragma unroll
            for (int msk = 1; msk < 16; msk <<= 1) mx = fmaxf(mx, __shfl_xor(mx, msk));
            const float mnew = fmaxf(mrun[r], mx);
            pscale[r] = __expf(mrun[r] - mnew);
            float smr = 0.0f;
#pragma unroll
            for (int n = 0; n < 4; ++n) {
                const float pv = __expf(sacc[n][r] - mnew);
                sacc[n][r] = pv;
                smr += pv;
            }
#pragma unroll
            for (int msk = 1; msk < 16; msk <<= 1) smr += __shfl_xor(smr, msk);
            lrun[r] = lrun[r] * pscale[r] + smr;
            mrun[r] = mnew;
        }
#pragma unroll
        for (int d = 0; d < 8; ++d)
#pragma unroll
            for (int r = 0; r < 4; ++r) o[d][r] *= pscale[r];

        __syncthreads();   // previous PV reads of P complete before overwrite
#pragma unroll
        for (int n = 0; n < 4; ++n)
#pragma unroll
            for (int r = 0; r < 4; ++r)
                P[w][l4 * 4 + r][n * 16 + l15] = __float2bfloat16(sacc[n][r]);
        __syncthreads();   // P visible

#pragma unroll
        for (int c = 0; c < 2; ++c) {
            short8 ap = *(const short8*)&P[w][l15][c * 32 + l4 * 8];
#pragma unroll
            for (int d = 0; d < 8; ++d) {
                short8 bv = *(const short8*)&vT[hV + (size_t)(d * 16 + l15) * S + kvb + c * 32 + l4 * 8];
                o[d] = __builtin_amdgcn_mfma_f32_16x16x32_bf16(ap, bv, o[d], 0, 0, 0);
            }
        }
    }

    // epilogue: normalize and write attnout bf16 in [B,S,D]
#pragma unroll
    for (int r = 0; r < 4; ++r) {
        const float inv = 1.0f / lrun[r];
        const int s_ = qr0 + l4 * 4 + r;
        const size_t obase = ((size_t)b_ * S + s_) * D + hh * HD;
#pragma unroll
        for (int d = 0; d < 8; ++d)
            out[obase + d * 16 + l15] = __float2bfloat16(o[d][r] * inv);
    }
}

extern "C" void kernel_launch(void* const* d_in, const int* in_sizes, int n_in,
                              void* d_out, int out_size, void* d_ws, size_t ws_size,
                              hipStream_t stream) {
    const float* x      = (const float*)d_in[0];
    const float* fc     = (const float*)d_in[1];
    const float* wqkv_w = (const float*)d_in[2];
    const float* wqkv_b = (const float*)d_in[3];
    const float* wo_w   = (const float*)d_in[4];
    const float* wo_b   = (const float*)d_in[5];
    const float* qn_w   = (const float*)d_in[6];
    const float* qn_b   = (const float*)d_in[7];
    const float* kn_w   = (const float*)d_in[8];
    const float* kn_b   = (const float*)d_in[9];
    float* out = (float*)d_out;
    char* ws = (char*)d_ws;

    bf16* xb = (bf16*)(ws);                    // 16.8 MB  [B*S][D]
    bf16* w1 = (bf16*)(ws + 16777216);         // 25.2 MB  [6144][2048]
    bf16* wo = (bf16*)(ws + 41943040);         // 8.4 MB   [2048][2048]
    bf16* qb = (bf16*)(ws + 50331648);         // 16.8 MB  [B][H][S][HD]
    bf16* kb = (bf16*)(ws + 67108864);         // 16.8 MB  [B][H][S][HD]
    bf16* vT = (bf16*)(ws + 83886080);         // 16.8 MB  [B][H][HD][S]
    bf16* ao = (bf16*)(ws + 100663296);        // 16.8 MB  [B*S][D]

    cvt_x_kernel<<<(S * B * D) / 256, 256, 0, stream>>>(x, xb);
    cvt_w_kernel<<<4096, 256, 0, stream>>>(wqkv_w, w1, N3 * D);
    cvt_w_kernel<<<2048, 256, 0, stream>>>(wo_w, wo, D * D);

    gemm_bt<0><<<dim3(N3 / 128, (B * S) / 128), 256, 0, stream>>>(
        xb, w1, wqkv_b, qb, kb, vT, nullptr);

    ln_rope_kernel<<<(B * H * S) / 4, 256, 0, stream>>>(qb, kb, fc, qn_w, qn_b, kn_w, kn_b);

    attn_kernel<<<dim3(S / 64, B * H), 256, 0, stream>>>(qb, kb, vT, ao);

    gemm_bt<1><<<dim3(D / 128, (B * S) / 128), 256, 0, stream>>>(
        ao, wo, wo_b, nullptr, nullptr, nullptr, out);
}

// Round 2
// 356.931 us; speedup vs baseline: 2.6788x; 2.6788x over previous
//
#include <hip/hip_runtime.h>
#include <hip/hip_bf16.h>

#define S 2048
#define B 2
#define D 2048
#define H 16
#define HD 128
#define N3 6144   // 3*D
#define KD 2048   // GEMM K dim

typedef __hip_bfloat16 bf16;
typedef float f32x4 __attribute__((ext_vector_type(4)));
typedef short short8 __attribute__((ext_vector_type(8)));

__device__ __forceinline__ void gload16(const void* g, void* l) {
    __builtin_amdgcn_global_load_lds((const __attribute__((address_space(1))) void*)g,
                                     (__attribute__((address_space(3))) void*)l, 16, 0, 0);
}

// ---------------- convert kernels ----------------
__global__ __launch_bounds__(256) void cvt_x_kernel(const float* __restrict__ x, bf16* __restrict__ xb) {
    int i = blockIdx.x * 256 + threadIdx.x;   // over [S][B][D]
    int d  = i & (D - 1);
    int sb = i >> 11;        // s*B + b
    int b  = sb & (B - 1);
    int s  = sb >> 1;
    xb[((size_t)(b * S + s) << 11) + d] = __float2bfloat16(x[i]);
}

__global__ __launch_bounds__(256) void cvt_w_kernel(const float* __restrict__ in, bf16* __restrict__ o, int n) {
    for (int i = blockIdx.x * blockDim.x + threadIdx.x; i < n; i += gridDim.x * blockDim.x)
        o[i] = __float2bfloat16(in[i]);
}

// ---------------- GEMM: out[m][n] = sum_k A[m][k] * W[n][k] + bias[n] ----------------
template <int MODE>
__global__ __launch_bounds__(256, 2) void gemm_bt(
    const bf16* __restrict__ A, const bf16* __restrict__ W, const float* __restrict__ bias,
    bf16* __restrict__ oq, bf16* __restrict__ ok, bf16* __restrict__ ovT,
    float* __restrict__ oOut)
{
    __shared__ __align__(16) bf16 At[128 * 32];
    __shared__ __align__(16) bf16 Bt[128 * 32];
    const int tid = threadIdx.x;
    const int w = tid >> 6, l = tid & 63;
    const int wm = w >> 1, wn = w & 1;
    const int l15 = l & 15, l4 = l >> 4;
    const int tileN = blockIdx.x * 128;
    const int tileM = blockIdx.y * 128;

    const int lr = l >> 2;          // row-within-16-row-chunk
    const int lc = (l & 3) * 8;     // k elem offset

    f32x4 acc[4][4] = {};

    for (int kt = 0; kt < KD / 32; ++kt) {
        const int k0 = kt * 32;
#pragma unroll
        for (int c = 0; c < 2; ++c) {
            const int chunk = c * 4 + w;               // 0..7, wave-uniform
            const int grow = chunk * 16 + lr;          // 0..127
            gload16(A + (size_t)(tileM + grow) * KD + k0 + lc, (char*)At + chunk * 1024);
            gload16(W + (size_t)(tileN + grow) * KD + k0 + lc, (char*)Bt + chunk * 1024);
        }
        __syncthreads();
        short8 af[4], bfr[4];
#pragma unroll
        for (int i = 0; i < 4; ++i)
            af[i] = *(const short8*)&At[(wm * 64 + i * 16 + l15) * 32 + l4 * 8];
#pragma unroll
        for (int j = 0; j < 4; ++j)
            bfr[j] = *(const short8*)&Bt[(wn * 64 + j * 16 + l15) * 32 + l4 * 8];
#pragma unroll
        for (int i = 0; i < 4; ++i)
#pragma unroll
            for (int j = 0; j < 4; ++j)
                acc[i][j] = __builtin_amdgcn_mfma_f32_16x16x32_bf16(af[i], bfr[j], acc[i][j], 0, 0, 0);
        __syncthreads();
    }

    // epilogue
#pragma unroll
    for (int i = 0; i < 4; ++i) {
#pragma unroll
        for (int j = 0; j < 4; ++j) {
            const int ncol = tileN + wn * 64 + j * 16 + l15;
            const float bv = bias[ncol];
#pragma unroll
            for (int r = 0; r < 4; ++r) {
                const int m = tileM + wm * 64 + i * 16 + l4 * 4 + r;
                const float val = acc[i][j][r] + bv;
                if (MODE == 0) {
                    const int b_ = m >> 11, s_ = m & (S - 1);
                    const int which = ncol >> 11;
                    const int hh = (ncol >> 7) & (H - 1);
                    const int hd = ncol & (HD - 1);
                    const int bh = b_ * H + hh;
                    if (which == 0)      oq[((size_t)bh * S + s_) * HD + hd] = __float2bfloat16(val);
                    else if (which == 1) ok[((size_t)bh * S + s_) * HD + hd] = __float2bfloat16(val);
                    else                 ovT[((size_t)bh * HD + hd) * S + s_] = __float2bfloat16(val);
                } else {
                    const int b_ = m >> 11, s_ = m & (S - 1);
                    oOut[((size_t)s_ * B + b_) * D + ncol] = val;
                }
            }
        }
    }
}

// ---------------- fused LayerNorm (over HD) + RoPE for q and k, in place ----------------
__global__ __launch_bounds__(256) void ln_rope_kernel(
    bf16* __restrict__ q, bf16* __restrict__ k,
    const float* __restrict__ fc,
    const float* __restrict__ qw, const float* __restrict__ qb,
    const float* __restrict__ kw, const float* __restrict__ kb)
{
    const int tid = threadIdx.x;
    const int w = tid >> 6, l = tid & 63;
    const int row = blockIdx.x * 4 + w;      // bh*S + s, 0..65535
    const int s_ = row & (S - 1);
    const size_t base = (size_t)row * HD;
    const float f0 = fc[s_ * HD + 2 * l];
    const float f1 = fc[s_ * HD + 2 * l + 1];

#pragma unroll
    for (int which = 0; which < 2; ++which) {
        bf16* p = which == 0 ? q : k;
        const float* gw = which == 0 ? qw : kw;
        const float* gb = which == 0 ? qb : kb;
        float x0 = __bfloat162float(p[base + 2 * l]);
        float x1 = __bfloat162float(p[base + 2 * l + 1]);
        float sm = x0 + x1;
#pragma unroll
        for (int msk = 1; msk < 64; msk <<= 1) sm += __shfl_xor(sm, msk);
        const float mu = sm * (1.0f / HD);
        const float d0 = x0 - mu, d1 = x1 - mu;
        float vs = d0 * d0 + d1 * d1;
#pragma unroll
        for (int msk = 1; msk < 64; msk <<= 1) vs += __shfl_xor(vs, msk);
        const float rstd = rsqrtf(vs * (1.0f / HD) + 1e-5f);
        const float n0 = d0 * rstd * gw[2 * l] + gb[2 * l];
        const float n1 = d1 * rstd * gw[2 * l + 1] + gb[2 * l + 1];
        p[base + 2 * l]     = __float2bfloat16(n0 * f0 - n1 * f1);
        p[base + 2 * l + 1] = __float2bfloat16(n1 * f0 + n0 * f1);
    }
}

// ---------------- causal flash attention v2 ----------------
// grid (32, 32) remapped internally: XCD-chunked (4 heads per XCD L2), heavy q-tiles first.
// Block = 4 waves, 64 q rows; K tile double-buffered LDS (swizzled), V tile single-buffered.
__global__ __launch_bounds__(256, 2) void attn_kernel(
    const bf16* __restrict__ q, const bf16* __restrict__ k, const bf16* __restrict__ vT,
    bf16* __restrict__ out)
{
    __shared__ __align__(16) bf16 KT[2][64 * 128];   // 2 x 16 KB, xor-swizzled rows
    __shared__ __align__(16) bf16 VS[128 * 64];      // 16 KB, xor-swizzled rows
    __shared__ __align__(16) bf16 Pb[4][16 * 72];    // per-wave P transpose

    const int tid = threadIdx.x, w = tid >> 6, l = tid & 63;
    const int l15 = l & 15, l4 = l >> 4;

    // block remap: contiguous 128-block chunk per XCD (4 heads), heavy q-tile first
    const int id  = blockIdx.y * gridDim.x + blockIdx.x;   // 0..1023
    const int nid = (id & 7) * 128 + (id >> 3);
    const int bh  = nid >> 5;                               // 0..31
    const int qt  = 31 - (nid & 31);                        // heavy first

    const int b_ = bh >> 4, hh = bh & (H - 1);
    const int qbase = qt * 64;
    const int qr0 = qbase + w * 16;
    const size_t hQ = (size_t)bh * S * HD;
    const size_t hV = (size_t)bh * HD * S;

    // staging offsets (bytes), per-lane invariant. LDS written linearly by gload_lds;
    // swizzle applied on the GLOBAL source so LDS[row][cb] = G[row][cb ^ f(row)].
    const char* kbase = (const char*)(k + hQ);
    const char* vbase = (const char*)(vT + hV);
    int ksrc[4], vsrc[4], kdst[4], vdst[4];
#pragma unroll
    for (int j = 0; j < 4; ++j) {
        const int ik = w * 4 + j;
        const int rt = ik * 4 + (l >> 4);            // K tile row 0..63
        ksrc[j] = rt * 256 + (((l & 15) * 16) ^ ((rt & 15) << 4));
        kdst[j] = ik * 1024;
        const int rd = ik * 8 + (l >> 3);            // V tile row (d) 0..127
        vsrc[j] = rd * (S * 2) + (((l & 7) * 16) ^ ((rd & 7) << 4));
        vdst[j] = ik * 1024;
    }

    short8 aq[4];
#pragma unroll
    for (int c = 0; c < 4; ++c)
        aq[c] = *(const short8*)&q[hQ + (size_t)(qr0 + l15) * HD + c * 32 + l4 * 8];

    f32x4 o[8] = {};
    float mrun[4], lrun[4];
#pragma unroll
    for (int r = 0; r < 4; ++r) { mrun[r] = -1e30f; lrun[r] = 0.0f; }

    // prologue: stage K tile 0
#pragma unroll
    for (int j = 0; j < 4; ++j)
        gload16(kbase + ksrc[j], (char*)KT[0] + kdst[j]);
    __syncthreads();

    int cur = 0;
    const int kx = l15 << 3;          // K read xor (elems): (row&15)<<3
    const int vx = (l15 & 7) << 3;    // V read xor (elems): (row&7)<<3

    for (int kvt = 0; kvt <= qt; ++kvt) {
        const int kvb = kvt * 64;
        // prefetch next K tile into other buffer
        if (kvt < qt) {
#pragma unroll
            for (int j = 0; j < 4; ++j)
                gload16(kbase + (size_t)(kvb + 64) * 256 + ksrc[j], (char*)KT[cur ^ 1] + kdst[j]);
        }
        // stage V tile for THIS iteration (safe: end-barrier of prev iter passed)
#pragma unroll
        for (int j = 0; j < 4; ++j)
            gload16(vbase + (size_t)kvb * 2 + vsrc[j], (char*)VS + vdst[j]);

        // QK^T from KT[cur]
        f32x4 sacc[4] = {};
#pragma unroll
        for (int c = 0; c < 4; ++c) {
            const int cole = (c * 32 + l4 * 8) ^ kx;
#pragma unroll
            for (int n = 0; n < 4; ++n) {
                short8 bk = *(const short8*)&KT[cur][(n * 16 + l15) * 128 + cole];
                sacc[n] = __builtin_amdgcn_mfma_f32_16x16x32_bf16(aq[c], bk, sacc[n], 0, 0, 0);
            }
        }

        const float sc = 0.08838834764831845f; // 1/sqrt(128)
        const bool diag = (kvb == qbase);
#pragma unroll
        for (int n = 0; n < 4; ++n)
#pragma unroll
            for (int r = 0; r < 4; ++r) {
                float sv = sacc[n][r] * sc;
                if (diag && (kvb + n * 16 + l15 > qr0 + l4 * 4 + r)) sv = -1e30f;
                sacc[n][r] = sv;
            }
        float pscale[4];
#pragma unroll
        for (int r = 0; r < 4; ++r) {
            float mx = fmaxf(fmaxf(sacc[0][r], sacc[1][r]), fmaxf(sacc[2][r], sacc[3][r]));
#pragma unroll
            for (int msk = 1; msk < 16; msk <<= 1) mx = fmaxf(mx, __shfl_xor(mx, msk));
            const float mnew = fmaxf(mrun[r], mx);
            pscale[r] = __expf(mrun[r] - mnew);
            float smr = 0.0f;
#pragma unroll
            for (int n = 0; n < 4; ++n) {
                const float pv = __expf(sacc[n][r] - mnew);
                sacc[n][r] = pv;
                smr += pv;
            }
#pragma unroll
            for (int msk = 1; msk < 16; msk <<= 1) smr += __shfl_xor(smr, msk);
            lrun[r] = lrun[r] * pscale[r] + smr;
            mrun[r] = mnew;
        }
#pragma unroll
        for (int d = 0; d < 8; ++d)
#pragma unroll
            for (int r = 0; r < 4; ++r) o[d][r] *= pscale[r];

        // per-wave P transpose through LDS (same-wave RAW: compiler inserts lgkmcnt)
#pragma unroll
        for (int n = 0; n < 4; ++n)
#pragma unroll
            for (int r = 0; r < 4; ++r)
                Pb[w][(l4 * 4 + r) * 72 + n * 16 + l15] = __float2bfloat16(sacc[n][r]);
        short8 ap[2];
#pragma unroll
        for (int c = 0; c < 2; ++c)
            ap[c] = *(const short8*)&Pb[w][l15 * 72 + c * 32 + l4 * 8];

        __syncthreads();   // mid barrier: V tile staged-complete (vmcnt drained)

        // PV from VS
#pragma unroll
        for (int c = 0; c < 2; ++c) {
#pragma unroll
            for (int d = 0; d < 8; ++d) {
                const int rd = d * 16 + l15;
                short8 bv = *(const short8*)&VS[rd * 64 + ((c * 32 + l4 * 8) ^ vx)];
                o[d] = __builtin_amdgcn_mfma_f32_16x16x32_bf16(ap[c], bv, o[d], 0, 0, 0);
            }
        }

        __syncthreads();   // end barrier: all waves done reading VS (and KT[cur])
        cur ^= 1;
    }

    // epilogue: normalize and write attnout bf16 in [B,S,D]
#pragma unroll
    for (int r = 0; r < 4; ++r) {
        const float inv = 1.0f / lrun[r];
        const int s_ = qr0 + l4 * 4 + r;
        const size_t obase = ((size_t)b_ * S + s_) * D + hh * HD;
#pragma unroll
        for (int d = 0; d < 8; ++d)
            out[obase + d * 16 + l15] = __float2bfloat16(o[d][r] * inv);
    }
}

extern "C" void kernel_launch(void* const* d_in, const int* in_sizes, int n_in,
                              void* d_out, int out_size, void* d_ws, size_t ws_size,
                              hipStream_t stream) {
    const float* x      = (const float*)d_in[0];
    const float* fc     = (const float*)d_in[1];
    const float* wqkv_w = (const float*)d_in[2];
    const float* wqkv_b = (const float*)d_in[3];
    const float* wo_w   = (const float*)d_in[4];
    const float* wo_b   = (const float*)d_in[5];
    const float* qn_w   = (const float*)d_in[6];
    const float* qn_b   = (const float*)d_in[7];
    const float* kn_w   = (const float*)d_in[8];
    const float* kn_b   = (const float*)d_in[9];
    float* out = (float*)d_out;
    char* ws = (char*)d_ws;

    bf16* xb = (bf16*)(ws);                    // [B*S][D]
    bf16* w1 = (bf16*)(ws + 16777216);         // [6144][2048]
    bf16* wo = (bf16*)(ws + 41943040);         // [2048][2048]
    bf16* qb = (bf16*)(ws + 50331648);         // [B][H][S][HD]
    bf16* kb = (bf16*)(ws + 67108864);         // [B][H][S][HD]
    bf16* vT = (bf16*)(ws + 83886080);         // [B][H][HD][S]
    bf16* ao = (bf16*)(ws + 100663296);        // [B*S][D]

    cvt_x_kernel<<<(S * B * D) / 256, 256, 0, stream>>>(x, xb);
    cvt_w_kernel<<<4096, 256, 0, stream>>>(wqkv_w, w1, N3 * D);
    cvt_w_kernel<<<2048, 256, 0, stream>>>(wo_w, wo, D * D);

    gemm_bt<0><<<dim3(N3 / 128, (B * S) / 128), 256, 0, stream>>>(
        xb, w1, wqkv_b, qb, kb, vT, nullptr);

    ln_rope_kernel<<<(B * H * S) / 4, 256, 0, stream>>>(qb, kb, fc, qn_w, qn_b, kn_w, kn_b);

    attn_kernel<<<dim3(S / 64, B * H), 256, 0, stream>>>(qb, kb, vT, ao);

    gemm_bt<1><<<dim3(D / 128, (B * S) / 128), 256, 0, stream>>>(
        ao, wo, wo_b, nullptr, nullptr, nullptr, out);
}